// Round 3
// baseline (2276.154 us; speedup 1.0000x reference)
//
#include <hip/hip_runtime.h>
#include <hip/hip_bf16.h>

typedef unsigned int u32;
typedef unsigned short u16;

#define T_STEPS 4
#define N_NODES 50000
#define E_EDGES 1600000
#define HID 128
#define OUT_CH 16

// ---- workspace layout (bytes) ----
#define OFF_H     0u            // h bf16 [N*128]            = 12,800,000
#define OFF_DEG   12800000u     // deg   [N] int             = 200,000
#define OFF_ZPAD  13000000u     // z_sum padded [128*32] f32 = 16,384  (contiguous w/ deg for one memset)
#define OFF_RS    13016384u     // row_start [N+1] int       = 200,004
#define OFF_CUR   13216640u     // cursor [N] int            = 200,000
#define OFF_CSR   13416704u     // csr src [E] u16           = 3,200,000  (u16: fits per-XCD L2 -> no writeback thrash)
#define OFF_HST   19816704u     // h_state [128] f32         = 512
#define OFF_WT    19817216u     // W_gcn transposed [128*128] f32 = 65,536

__device__ __forceinline__ float bflo(u32 u) { return __uint_as_float(u << 16); }
__device__ __forceinline__ float bfhi(u32 u) { return __uint_as_float(u & 0xFFFF0000u); }

// Wt[k*128 + c] = W[c*128 + k]; run once per launch (W constant across steps)
__global__ void transpose_kernel(const float* __restrict__ W, float* __restrict__ Wt) {
    const int i = blockIdx.x * 256 + threadIdx.x;   // 16384 total
    const int c = i >> 7, k = i & 127;
    Wt[k * 128 + c] = W[c * 128 + k];
}

// h = bf16( x @ W^T + b ), x:[N,128], Wt:[k][c] (transposed for coalesced reload)
// Wave = 64 output channels (half = wv&1) x 16 nodes. k tiled by 32:
// wreg[32] coalesced from Wt (L1-hit), x elements wave-uniform (broadcast/scalar).
// Peak live regs ~ 32 wreg + 16 acc + addressing: no spill (R0 lesson: wreg[128] spilled).
__global__ __launch_bounds__(256) void gemm_kernel(const float* __restrict__ x,
                                                   const float* __restrict__ Wt,
                                                   const float* __restrict__ b,
                                                   __hip_bfloat16* __restrict__ h) {
    const int lane = threadIdx.x & 63;
    const int wv   = __builtin_amdgcn_readfirstlane((int)(threadIdx.x >> 6));
    const int c    = (wv & 1) * 64 + lane;   // output channel
    const float bias = b[c];

    const int nGroups = N_NODES / 16;        // 3125
    int g = blockIdx.x * 2 + (wv >> 1);
    const int gstr = gridDim.x * 2;
    for (; g < nGroups; g += gstr) {
        const int n0 = g * 16;
        const float* xr = x + (size_t)n0 * 128;
        float acc[16];
#pragma unroll
        for (int i = 0; i < 16; ++i) acc[i] = 0.f;

        for (int kc = 0; kc < 128; kc += 32) {
            float wreg[32];
#pragma unroll
            for (int j = 0; j < 32; ++j) wreg[j] = Wt[(kc + j) * 128 + c];
#pragma unroll
            for (int n = 0; n < 16; ++n) {
                const float* xn = xr + n * 128 + kc;
#pragma unroll
                for (int j = 0; j < 32; ++j) acc[n] = fmaf(xn[j], wreg[j], acc[n]);
            }
        }
#pragma unroll
        for (int n = 0; n < 16; ++n)
            h[(size_t)(n0 + n) * 128 + c] = __float2bfloat16(acc[n] + bias);
    }
}

__global__ void count_kernel(const int4* __restrict__ dst4, int* __restrict__ deg) {
    int i = blockIdx.x * blockDim.x + threadIdx.x;
    const int str = gridDim.x * blockDim.x;
    const int n4 = E_EDGES / 4;
    for (; i < n4; i += str) {
        const int4 v = dst4[i];
        atomicAdd(&deg[v.x], 1);
        atomicAdd(&deg[v.y], 1);
        atomicAdd(&deg[v.z], 1);
        atomicAdd(&deg[v.w], 1);
    }
}

// single-block exclusive scan of deg -> row_start, cursor; row_start[N]=E
__global__ void scan_kernel(const int* __restrict__ deg,
                            int* __restrict__ row_start,
                            int* __restrict__ cursor) {
    __shared__ int part[1024];
    const int tid = threadIdx.x;
    const int chunk = (N_NODES + 1023) / 1024;   // 49
    const int begin = tid * chunk;
    const int end   = min(begin + chunk, N_NODES);
    int s = 0;
    for (int i = begin; i < end; ++i) s += deg[i];
    part[tid] = s;
    __syncthreads();
    for (int d = 1; d < 1024; d <<= 1) {
        int v = (tid >= d) ? part[tid - d] : 0;
        __syncthreads();
        part[tid] += v;
        __syncthreads();
    }
    int run = (tid == 0) ? 0 : part[tid - 1];
    for (int i = begin; i < end; ++i) {
        row_start[i] = run;
        cursor[i]    = run;
        run += deg[i];
    }
    if (tid == 1023) row_start[N_NODES] = part[1023];
}

__global__ void fill_kernel(const int4* __restrict__ src4, const int4* __restrict__ dst4,
                            int* __restrict__ cursor, u16* __restrict__ csr) {
    int i = blockIdx.x * blockDim.x + threadIdx.x;
    const int str = gridDim.x * blockDim.x;
    const int n4 = E_EDGES / 4;
    for (; i < n4; i += str) {
        const int4 s = src4[i];
        const int4 d = dst4[i];
        const int p0 = atomicAdd(&cursor[d.x], 1);
        const int p1 = atomicAdd(&cursor[d.y], 1);
        const int p2 = atomicAdd(&cursor[d.z], 1);
        const int p3 = atomicAdd(&cursor[d.w], 1);
        csr[p0] = (u16)s.x;
        csr[p1] = (u16)s.y;
        csr[p2] = (u16)s.z;
        csr[p3] = (u16)s.w;
    }
}

// One wave per dst node. Lane holds channels (2*lane, 2*lane+1) as one dword of bf16x2.
// src indices are wave-uniform; each src row read = coalesced 256B.
// Per-node: acc = h[n] (self loop) + sum h[src]; z += relu(acc/(cnt+1)).
__global__ __launch_bounds__(256) void gather_kernel(const u32* __restrict__ h2,
                                                     const int* __restrict__ row_start,
                                                     const u16* __restrict__ csr,
                                                     float* __restrict__ z_pad) {
    const int lane = threadIdx.x & 63;
    const int wv   = __builtin_amdgcn_readfirstlane((int)(threadIdx.x >> 6));
    const int gw   = blockIdx.x * 4 + wv;
    const int nw   = gridDim.x * 4;

    float zx = 0.f, zy = 0.f;
    for (int n = gw; n < N_NODES; n += nw) {
        const int rs  = row_start[n];
        const int cnt = row_start[n + 1] - rs;
        const u32 us = h2[n * 64 + lane];          // self loop
        float ax = bflo(us), ay = bfhi(us);
        const u16* lst = csr + rs;
        int i = 0;
        for (; i + 4 <= cnt; i += 4) {
            const int s0 = lst[i], s1 = lst[i + 1], s2 = lst[i + 2], s3 = lst[i + 3];
            const u32 u0 = h2[s0 * 64 + lane];
            const u32 u1 = h2[s1 * 64 + lane];
            const u32 u2 = h2[s2 * 64 + lane];
            const u32 u3 = h2[s3 * 64 + lane];
            ax += bflo(u0) + bflo(u1) + bflo(u2) + bflo(u3);
            ay += bfhi(u0) + bfhi(u1) + bfhi(u2) + bfhi(u3);
        }
        for (; i < cnt; ++i) {
            const u32 u0 = h2[lst[i] * 64 + lane];
            ax += bflo(u0);
            ay += bfhi(u0);
        }
        const float inv = 1.0f / (float)(cnt + 1);
        zx += fmaxf(ax * inv, 0.f);
        zy += fmaxf(ay * inv, 0.f);
    }

    __shared__ float red[4][64][2];
    red[wv][lane][0] = zx;
    red[wv][lane][1] = zy;
    __syncthreads();
    if (threadIdx.x < 64) {
        const float sx = red[0][lane][0] + red[1][lane][0] + red[2][lane][0] + red[3][lane][0];
        const float sy = red[0][lane][1] + red[1][lane][1] + red[2][lane][1] + red[3][lane][1];
        atomicAdd(&z_pad[(2 * lane) * 32], sx);       // 128B-strided slots: no same-line atomic pileup
        atomicAdd(&z_pad[(2 * lane + 1) * 32], sy);
    }
}

__global__ __launch_bounds__(512) void gru_kernel(const float* __restrict__ z_pad,
                                                  const float* __restrict__ W_ih,
                                                  const float* __restrict__ W_hh,
                                                  const float* __restrict__ b_ih,
                                                  const float* __restrict__ b_hh,
                                                  float* __restrict__ h_state,
                                                  const float* __restrict__ W_cls,
                                                  const float* __restrict__ b_cls,
                                                  float* __restrict__ out,
                                                  int do_cls) {
    __shared__ float zm[128], hs[128], gi[384], gh[384], hn[128];
    const int tid = threadIdx.x;
    if (tid < 128) {
        zm[tid] = z_pad[tid * 32] * (1.0f / (float)N_NODES);
        hs[tid] = h_state[tid];
    }
    __syncthreads();
    if (tid < 384) {
        float a = b_ih[tid], g = b_hh[tid];
        const float* wi = W_ih + tid * 128;
        const float* wh = W_hh + tid * 128;
#pragma unroll 8
        for (int k = 0; k < 128; ++k) {
            a = fmaf(zm[k], wi[k], a);
            g = fmaf(hs[k], wh[k], g);
        }
        gi[tid] = a;
        gh[tid] = g;
    }
    __syncthreads();
    if (tid < 128) {
        const float r  = 1.f / (1.f + expf(-(gi[tid] + gh[tid])));
        const float zg = 1.f / (1.f + expf(-(gi[128 + tid] + gh[128 + tid])));
        const float ng = tanhf(gi[256 + tid] + r * gh[256 + tid]);
        const float hv = (1.f - zg) * ng + zg * hs[tid];
        h_state[tid] = hv;
        hn[tid] = hv;
    }
    __syncthreads();
    if (do_cls && tid < OUT_CH) {
        float a = b_cls[tid];
        const float* wc = W_cls + tid * 128;
#pragma unroll 8
        for (int k = 0; k < 128; ++k) a = fmaf(hn[k], wc[k], a);
        out[tid] = a;
    }
}

extern "C" void kernel_launch(void* const* d_in, const int* in_sizes, int n_in,
                              void* d_out, int out_size, void* d_ws, size_t ws_size,
                              hipStream_t stream) {
    const float* xs    = (const float*)d_in[0];
    const int*   edges = (const int*)d_in[1];
    const float* W_gcn = (const float*)d_in[2];
    const float* b_gcn = (const float*)d_in[3];
    const float* W_ih  = (const float*)d_in[4];
    const float* W_hh  = (const float*)d_in[5];
    const float* b_ih  = (const float*)d_in[6];
    const float* b_hh  = (const float*)d_in[7];
    const float* W_cls = (const float*)d_in[8];
    const float* b_cls = (const float*)d_in[9];
    float* out = (float*)d_out;

    char* ws = (char*)d_ws;
    __hip_bfloat16* h = (__hip_bfloat16*)(ws + OFF_H);
    int*   deg       = (int*)(ws + OFF_DEG);
    float* z_pad     = (float*)(ws + OFF_ZPAD);
    int*   row_start = (int*)(ws + OFF_RS);
    int*   cursor    = (int*)(ws + OFF_CUR);
    u16*   csr       = (u16*)(ws + OFF_CSR);
    float* h_state   = (float*)(ws + OFF_HST);
    float* Wt        = (float*)(ws + OFF_WT);

    hipMemsetAsync(h_state, 0, 128 * sizeof(float), stream);
    transpose_kernel<<<64, 256, 0, stream>>>(W_gcn, Wt);

    for (int t = 0; t < T_STEPS; ++t) {
        const float* x_t  = xs + (size_t)t * N_NODES * 128;
        const int* src_t  = edges + (size_t)t * 2 * E_EDGES;
        const int* dst_t  = src_t + E_EDGES;

        // zero deg + z_pad (contiguous region)
        hipMemsetAsync(deg, 0, 200000 + 16384, stream);

        gemm_kernel<<<782, 256, 0, stream>>>(x_t, Wt, b_gcn, h);
        count_kernel<<<1024, 256, 0, stream>>>((const int4*)dst_t, deg);
        scan_kernel<<<1, 1024, 0, stream>>>(deg, row_start, cursor);
        fill_kernel<<<1024, 256, 0, stream>>>((const int4*)src_t, (const int4*)dst_t, cursor, csr);
        gather_kernel<<<1024, 256, 0, stream>>>((const u32*)h, row_start, csr, z_pad);
        gru_kernel<<<1, 512, 0, stream>>>(z_pad, W_ih, W_hh, b_ih, b_hh, h_state,
                                          W_cls, b_cls, out, (t == T_STEPS - 1) ? 1 : 0);
    }
}

// Round 4
// 1862.532 us; speedup vs baseline: 1.2221x; 1.2221x over previous
//
#include <hip/hip_runtime.h>
#include <hip/hip_bf16.h>

typedef unsigned int u32;
typedef unsigned short u16;

#define T_STEPS 4
#define N_NODES 50000
#define E_EDGES 1600000
#define HID 128
#define OUT_CH 16

#define NB 128                   // hist blocks; chunk = E/NB
#define CHUNK (E_EDGES / NB)     // 12500
#define NPAIR (N_NODES / 2)      // 25000 packed u16-pair histogram entries

// ---- workspace layout (bytes) ----
#define OFF_H     0u            // h bf16 [N*128]            = 12,800,000
#define OFF_DEG   12800000u     // deg   [N] int             = 200,000
#define OFF_ZPAD  13000000u     // z_sum padded [128*32] f32 = 16,384
#define OFF_RS    13016384u     // row_start [N+1] int       = 200,004
#define OFF_CSR   13216640u     // csr src [E] u16           = 3,200,000
#define OFF_HST   16416640u     // h_state [128] f32         = 512
#define OFF_WT    16417152u     // W_gcn transposed          = 65,536
#define OFF_RANKS 16482688u     // ranks [E] u16             = 3,200,000
#define OFF_HIST  19682688u     // hist [NB][NPAIR] u32      = 12,800,000  (end ~32.5 MB)

__device__ __forceinline__ float bflo(u32 u) { return __uint_as_float(u << 16); }
__device__ __forceinline__ float bfhi(u32 u) { return __uint_as_float(u & 0xFFFF0000u); }

// Wt[k*128 + c] = W[c*128 + k]; once per launch
__global__ void transpose_kernel(const float* __restrict__ W, float* __restrict__ Wt) {
    const int i = blockIdx.x * 256 + threadIdx.x;
    const int c = i >> 7, k = i & 127;
    Wt[k * 128 + c] = W[c * 128 + k];
}

// h = bf16( x @ W^T + b ). Wave = 64 channels x 16 nodes; k tiled by 32 so peak
// live regs ~55 (R0 lesson: wreg[128] spilled to scratch -> 575 MB FETCH).
__global__ __launch_bounds__(256) void gemm_kernel(const float* __restrict__ x,
                                                   const float* __restrict__ Wt,
                                                   const float* __restrict__ b,
                                                   __hip_bfloat16* __restrict__ h) {
    const int lane = threadIdx.x & 63;
    const int wv   = __builtin_amdgcn_readfirstlane((int)(threadIdx.x >> 6));
    const int c    = (wv & 1) * 64 + lane;
    const float bias = b[c];

    const int nGroups = N_NODES / 16;        // 3125
    int g = blockIdx.x * 2 + (wv >> 1);
    const int gstr = gridDim.x * 2;
    for (; g < nGroups; g += gstr) {
        const int n0 = g * 16;
        const float* xr = x + (size_t)n0 * 128;
        float acc[16];
#pragma unroll
        for (int i = 0; i < 16; ++i) acc[i] = 0.f;

        for (int kc = 0; kc < 128; kc += 32) {
            float wreg[32];
#pragma unroll
            for (int j = 0; j < 32; ++j) wreg[j] = Wt[(kc + j) * 128 + c];
#pragma unroll
            for (int n = 0; n < 16; ++n) {
                const float* xn = xr + n * 128 + kc;
#pragma unroll
                for (int j = 0; j < 32; ++j) acc[n] = fmaf(xn[j], wreg[j], acc[n]);
            }
        }
#pragma unroll
        for (int n = 0; n < 16; ++n)
            h[(size_t)(n0 + n) * 128 + c] = __float2bfloat16(acc[n] + bias);
    }
}

// Block b: LDS histogram of its 12500-edge chunk (u16 counts packed 2/u32),
// LDS-atomic return = local rank. Two node-halves (50 KB LDS each) to stay
// under the 64 KB/WG static-LDS limit. No global atomics (R3 lesson: 1.6M
// device-scope atomics = 103 MB EA round-trips = the whole fill cost).
__global__ __launch_bounds__(256) void hist_rank_kernel(const int* __restrict__ dst,
                                                        u32* __restrict__ hist,
                                                        u16* __restrict__ ranks) {
    __shared__ u32 hloc[NPAIR / 2];          // 12500 u32 = 50 KB
    const int b = blockIdx.x;
    const int base = b * CHUNK;
    u32* row = hist + (size_t)b * NPAIR;

#pragma unroll
    for (int half = 0; half < 2; ++half) {
        for (int j = threadIdx.x; j < NPAIR / 2; j += 256) hloc[j] = 0;
        __syncthreads();
        const int jlo = half * (NPAIR / 2);
        for (int i = threadIdx.x; i < CHUNK; i += 256) {
            const int d = dst[base + i];
            const int j = d >> 1;
            if ((j >= jlo) && (j < jlo + NPAIR / 2)) {
                const u32 inc = (d & 1) ? 0x10000u : 1u;
                const u32 old = atomicAdd(&hloc[j - jlo], inc);
                ranks[base + i] = (u16)((old >> ((d & 1) * 16)) & 0xFFFFu);
            }
        }
        __syncthreads();
        for (int j = threadIdx.x; j < NPAIR / 2; j += 256) row[jlo + j] = hloc[j];
        __syncthreads();
    }
}

// In-place exclusive scan over the NB block-rows for each node pair; emits deg.
// Coalesced: lanes j..j+63 read/write consecutive u32s for each b.
__global__ void colscan_kernel(u32* __restrict__ hist, int* __restrict__ deg) {
    const int j = blockIdx.x * blockDim.x + threadIdx.x;
    if (j >= NPAIR) return;
    u32 lo = 0, hi = 0;
    u32* p = hist + j;
#pragma unroll 4
    for (int b = 0; b < NB; ++b) {
        const u32 v = p[(size_t)b * NPAIR];
        p[(size_t)b * NPAIR] = lo | (hi << 16);
        lo += v & 0xFFFFu;
        hi += v >> 16;
    }
    deg[2 * j]     = (int)lo;
    deg[2 * j + 1] = (int)hi;
}

// single-block exclusive scan of deg -> row_start; row_start[N]=E
__global__ void scan_kernel(const int* __restrict__ deg,
                            int* __restrict__ row_start) {
    __shared__ int part[1024];
    const int tid = threadIdx.x;
    const int chunk = (N_NODES + 1023) / 1024;   // 49
    const int begin = tid * chunk;
    const int end   = min(begin + chunk, N_NODES);
    int s = 0;
    for (int i = begin; i < end; ++i) s += deg[i];
    part[tid] = s;
    __syncthreads();
    for (int d = 1; d < 1024; d <<= 1) {
        int v = (tid >= d) ? part[tid - d] : 0;
        __syncthreads();
        part[tid] += v;
        __syncthreads();
    }
    int run = (tid == 0) ? 0 : part[tid - 1];
    for (int i = begin; i < end; ++i) {
        row_start[i] = run;
        run += deg[i];
    }
    if (tid == 1023) row_start[N_NODES] = part[1023];
}

// pos = row_start[d] + colscan[b][d] + local_rank  -- atomic-free CSR fill.
__global__ __launch_bounds__(256) void fill_kernel(const int* __restrict__ src,
                                                   const int* __restrict__ dst,
                                                   const u16* __restrict__ ranks,
                                                   const int* __restrict__ row_start,
                                                   const u32* __restrict__ hist,
                                                   u16* __restrict__ csr) {
    const int b = blockIdx.x;
    const u32* cs = hist + (size_t)b * NPAIR;
    const int base = b * CHUNK;
    for (int i = threadIdx.x; i < CHUNK; i += 256) {
        const int d = dst[base + i];
        const int s = src[base + i];
        const int r = ranks[base + i];
        const int off = (int)((cs[d >> 1] >> ((d & 1) * 16)) & 0xFFFFu);
        csr[row_start[d] + off + r] = (u16)s;
    }
}

// One wave per dst node; lane = bf16x2 channel pair; coalesced 256B row reads.
__global__ __launch_bounds__(256) void gather_kernel(const u32* __restrict__ h2,
                                                     const int* __restrict__ row_start,
                                                     const u16* __restrict__ csr,
                                                     float* __restrict__ z_pad) {
    const int lane = threadIdx.x & 63;
    const int wv   = __builtin_amdgcn_readfirstlane((int)(threadIdx.x >> 6));
    const int gw   = blockIdx.x * 4 + wv;
    const int nw   = gridDim.x * 4;

    float zx = 0.f, zy = 0.f;
    for (int n = gw; n < N_NODES; n += nw) {
        const int rs  = row_start[n];
        const int cnt = row_start[n + 1] - rs;
        const u32 us = h2[n * 64 + lane];          // self loop
        float ax = bflo(us), ay = bfhi(us);
        const u16* lst = csr + rs;
        int i = 0;
        for (; i + 4 <= cnt; i += 4) {
            const int s0 = lst[i], s1 = lst[i + 1], s2 = lst[i + 2], s3 = lst[i + 3];
            const u32 u0 = h2[s0 * 64 + lane];
            const u32 u1 = h2[s1 * 64 + lane];
            const u32 u2 = h2[s2 * 64 + lane];
            const u32 u3 = h2[s3 * 64 + lane];
            ax += bflo(u0) + bflo(u1) + bflo(u2) + bflo(u3);
            ay += bfhi(u0) + bfhi(u1) + bfhi(u2) + bfhi(u3);
        }
        for (; i < cnt; ++i) {
            const u32 u0 = h2[lst[i] * 64 + lane];
            ax += bflo(u0);
            ay += bfhi(u0);
        }
        const float inv = 1.0f / (float)(cnt + 1);
        zx += fmaxf(ax * inv, 0.f);
        zy += fmaxf(ay * inv, 0.f);
    }

    __shared__ float red[4][64][2];
    red[wv][lane][0] = zx;
    red[wv][lane][1] = zy;
    __syncthreads();
    if (threadIdx.x < 64) {
        const float sx = red[0][lane][0] + red[1][lane][0] + red[2][lane][0] + red[3][lane][0];
        const float sy = red[0][lane][1] + red[1][lane][1] + red[2][lane][1] + red[3][lane][1];
        atomicAdd(&z_pad[(2 * lane) * 32], sx);       // 128 slots, 128B apart
        atomicAdd(&z_pad[(2 * lane + 1) * 32], sy);
    }
}

__global__ __launch_bounds__(512) void gru_kernel(const float* __restrict__ z_pad,
                                                  const float* __restrict__ W_ih,
                                                  const float* __restrict__ W_hh,
                                                  const float* __restrict__ b_ih,
                                                  const float* __restrict__ b_hh,
                                                  float* __restrict__ h_state,
                                                  const float* __restrict__ W_cls,
                                                  const float* __restrict__ b_cls,
                                                  float* __restrict__ out,
                                                  int do_cls) {
    __shared__ float zm[128], hs[128], gi[384], gh[384], hn[128];
    const int tid = threadIdx.x;
    if (tid < 128) {
        zm[tid] = z_pad[tid * 32] * (1.0f / (float)N_NODES);
        hs[tid] = h_state[tid];
    }
    __syncthreads();
    if (tid < 384) {
        float a = b_ih[tid], g = b_hh[tid];
        const float* wi = W_ih + tid * 128;
        const float* wh = W_hh + tid * 128;
#pragma unroll 8
        for (int k = 0; k < 128; ++k) {
            a = fmaf(zm[k], wi[k], a);
            g = fmaf(hs[k], wh[k], g);
        }
        gi[tid] = a;
        gh[tid] = g;
    }
    __syncthreads();
    if (tid < 128) {
        const float r  = 1.f / (1.f + expf(-(gi[tid] + gh[tid])));
        const float zg = 1.f / (1.f + expf(-(gi[128 + tid] + gh[128 + tid])));
        const float ng = tanhf(gi[256 + tid] + r * gh[256 + tid]);
        const float hv = (1.f - zg) * ng + zg * hs[tid];
        h_state[tid] = hv;
        hn[tid] = hv;
    }
    __syncthreads();
    if (do_cls && tid < OUT_CH) {
        float a = b_cls[tid];
        const float* wc = W_cls + tid * 128;
#pragma unroll 8
        for (int k = 0; k < 128; ++k) a = fmaf(hn[k], wc[k], a);
        out[tid] = a;
    }
}

extern "C" void kernel_launch(void* const* d_in, const int* in_sizes, int n_in,
                              void* d_out, int out_size, void* d_ws, size_t ws_size,
                              hipStream_t stream) {
    const float* xs    = (const float*)d_in[0];
    const int*   edges = (const int*)d_in[1];
    const float* W_gcn = (const float*)d_in[2];
    const float* b_gcn = (const float*)d_in[3];
    const float* W_ih  = (const float*)d_in[4];
    const float* W_hh  = (const float*)d_in[5];
    const float* b_ih  = (const float*)d_in[6];
    const float* b_hh  = (const float*)d_in[7];
    const float* W_cls = (const float*)d_in[8];
    const float* b_cls = (const float*)d_in[9];
    float* out = (float*)d_out;

    char* ws = (char*)d_ws;
    __hip_bfloat16* h = (__hip_bfloat16*)(ws + OFF_H);
    int*   deg       = (int*)(ws + OFF_DEG);
    float* z_pad     = (float*)(ws + OFF_ZPAD);
    int*   row_start = (int*)(ws + OFF_RS);
    u16*   csr       = (u16*)(ws + OFF_CSR);
    float* h_state   = (float*)(ws + OFF_HST);
    float* Wt        = (float*)(ws + OFF_WT);
    u16*   ranks     = (u16*)(ws + OFF_RANKS);
    u32*   hist      = (u32*)(ws + OFF_HIST);

    hipMemsetAsync(h_state, 0, 128 * sizeof(float), stream);
    transpose_kernel<<<64, 256, 0, stream>>>(W_gcn, Wt);

    for (int t = 0; t < T_STEPS; ++t) {
        const float* x_t  = xs + (size_t)t * N_NODES * 128;
        const int* src_t  = edges + (size_t)t * 2 * E_EDGES;
        const int* dst_t  = src_t + E_EDGES;

        hipMemsetAsync(z_pad, 0, 16384, stream);

        gemm_kernel<<<782, 256, 0, stream>>>(x_t, Wt, b_gcn, h);
        hist_rank_kernel<<<NB, 256, 0, stream>>>(dst_t, hist, ranks);
        colscan_kernel<<<(NPAIR + 255) / 256, 256, 0, stream>>>(hist, deg);
        scan_kernel<<<1, 1024, 0, stream>>>(deg, row_start);
        fill_kernel<<<NB, 256, 0, stream>>>(src_t, dst_t, ranks, row_start, hist, csr);
        gather_kernel<<<1024, 256, 0, stream>>>((const u32*)h, row_start, csr, z_pad);
        gru_kernel<<<1, 512, 0, stream>>>(z_pad, W_ih, W_hh, b_ih, b_hh, h_state,
                                          W_cls, b_cls, out, (t == T_STEPS - 1) ? 1 : 0);
    }
}

// Round 5
// 1259.191 us; speedup vs baseline: 1.8076x; 1.4791x over previous
//
#include <hip/hip_runtime.h>
#include <hip/hip_bf16.h>

typedef unsigned int u32;
typedef unsigned short u16;
typedef __attribute__((ext_vector_type(8))) __bf16 bfrag;   // 8 bf16 = 4 VGPRs (MFMA A/B operand)
typedef __attribute__((ext_vector_type(4))) float f32x4;    // MFMA C/D

#define T_STEPS 4
#define N_NODES 50000
#define E_EDGES 1600000
#define HID 128
#define OUT_CH 16

#define NB 128                   // hist blocks; chunk = E/NB
#define CHUNK (E_EDGES / NB)     // 12500
#define NPAIR (N_NODES / 2)      // 25000 packed u16-pair histogram entries

// ---- workspace layout (bytes) ----
#define OFF_H     0u            // h bf16 [N*128]            = 12,800,000
#define OFF_DEG   12800000u     // deg   [N] int             = 200,000
#define OFF_ZPAD  13000000u     // z_sum padded [128*32] f32 = 16,384
#define OFF_RS    13016384u     // row_start [N+1] int       = 200,004
#define OFF_CSR   13216640u     // csr src [E] u16           = 3,200,000
#define OFF_HST   16416640u     // h_state [128] f32         = 512
#define OFF_WB    16417152u     // W_gcn bf16 [128*128]      = 32,768 (in old Wt slot)
#define OFF_RANKS 16482688u     // ranks [E] u16             = 3,200,000
#define OFF_HIST  19682688u     // hist [NB][NPAIR] u32      = 12,800,000  (end ~32.5 MB)

__device__ __forceinline__ float bflo(u32 u) { return __uint_as_float(u << 16); }
__device__ __forceinline__ float bfhi(u32 u) { return __uint_as_float(u & 0xFFFF0000u); }

// one-shot: W fp32 -> bf16 (32 KB, L1-resident for the GEMM)
__global__ void wbf_kernel(const float* __restrict__ W, __bf16* __restrict__ wb) {
    const int i = blockIdx.x * 256 + threadIdx.x;   // 16384
    wb[i] = (__bf16)W[i];
}

// h = bf16(x @ W^T + b) via MFMA 16x16x32 bf16.
// Block = 16-row m-tile (3125 blocks), 4 waves; wave wv covers output cols [32wv,32wv+32).
// Frag layouts (m89/m120-verified): A[m=lane&15][k=(lane>>4)*8+j],
// B[n=lane&15][k=(lane>>4)*8+j], C/D row=(lane>>4)*4+reg, col=lane&15.
// A built from fp32 x in-reg (coalesced loads + cvt); B preloaded from bf16 W
// (row-major [c][k] is exactly frag-contiguous: 8 bf16 = one dwordx4).
__global__ __launch_bounds__(256) void gemm_mfma_kernel(const float* __restrict__ x,
                                                        const __bf16* __restrict__ wb,
                                                        const float* __restrict__ b,
                                                        __hip_bfloat16* __restrict__ h) {
    const int lane = threadIdx.x & 63;
    const int wv   = threadIdx.x >> 6;      // 0..3 -> n-slice
    const int r16  = lane & 15;
    const int quad = lane >> 4;
    const int mb   = blockIdx.x;            // rows [16mb, 16mb+16)

    // B frags: 2 n-tiles x 4 k-steps
    bfrag Bf[2][4];
#pragma unroll
    for (int nt = 0; nt < 2; ++nt) {
        const int c = wv * 32 + nt * 16 + r16;
#pragma unroll
        for (int ks = 0; ks < 4; ++ks)
            Bf[nt][ks] = *(const bfrag*)(wb + c * 128 + ks * 32 + quad * 8);
    }

    // A frags: 4 k-steps, from fp32 x
    const float* xp = x + (size_t)(mb * 16 + r16) * 128 + quad * 8;
    bfrag Af[4];
#pragma unroll
    for (int ks = 0; ks < 4; ++ks) {
        const float* ap = xp + ks * 32;
#pragma unroll
        for (int j = 0; j < 8; ++j) Af[ks][j] = (__bf16)ap[j];
    }

    f32x4 acc0 = {0.f, 0.f, 0.f, 0.f};
    f32x4 acc1 = {0.f, 0.f, 0.f, 0.f};
#pragma unroll
    for (int ks = 0; ks < 4; ++ks) {
        acc0 = __builtin_amdgcn_mfma_f32_16x16x32_bf16(Af[ks], Bf[0][ks], acc0, 0, 0, 0);
        acc1 = __builtin_amdgcn_mfma_f32_16x16x32_bf16(Af[ks], Bf[1][ks], acc1, 0, 0, 0);
    }

    const int c0 = wv * 32 + r16;
    const float b0 = b[c0], b1 = b[c0 + 16];
#pragma unroll
    for (int r = 0; r < 4; ++r) {
        const int row = mb * 16 + quad * 4 + r;
        h[(size_t)row * 128 + c0]      = __float2bfloat16(acc0[r] + b0);
        h[(size_t)row * 128 + c0 + 16] = __float2bfloat16(acc1[r] + b1);
    }
}

// Block b: LDS histogram of its 12500-edge chunk (u16 counts packed 2/u32),
// LDS-atomic return = local rank. Two node-halves (50 KB LDS each). No global
// atomics (R3 lesson: 1.6M device-scope atomics = 103 MB EA round-trips).
__global__ __launch_bounds__(512) void hist_rank_kernel(const int* __restrict__ dst,
                                                        u32* __restrict__ hist,
                                                        u16* __restrict__ ranks) {
    __shared__ u32 hloc[NPAIR / 2];          // 12500 u32 = 50 KB
    const int b = blockIdx.x;
    const int base = b * CHUNK;
    u32* row = hist + (size_t)b * NPAIR;

#pragma unroll
    for (int half = 0; half < 2; ++half) {
        for (int j = threadIdx.x; j < NPAIR / 2; j += 512) hloc[j] = 0;
        __syncthreads();
        const int jlo = half * (NPAIR / 2);
        for (int i = threadIdx.x; i < CHUNK; i += 512) {
            const int d = dst[base + i];
            const int j = d >> 1;
            if ((j >= jlo) && (j < jlo + NPAIR / 2)) {
                const u32 inc = (d & 1) ? 0x10000u : 1u;
                const u32 old = atomicAdd(&hloc[j - jlo], inc);
                ranks[base + i] = (u16)((old >> ((d & 1) * 16)) & 0xFFFFu);
            }
        }
        __syncthreads();
        for (int j = threadIdx.x; j < NPAIR / 2; j += 512) row[jlo + j] = hloc[j];
        __syncthreads();
    }
}

// In-place exclusive scan over the NB block-rows for each node pair; emits deg.
__global__ void colscan_kernel(u32* __restrict__ hist, int* __restrict__ deg) {
    const int j = blockIdx.x * blockDim.x + threadIdx.x;
    if (j >= NPAIR) return;
    u32 lo = 0, hi = 0;
    u32* p = hist + j;
#pragma unroll 8
    for (int b = 0; b < NB; ++b) {
        const u32 v = p[(size_t)b * NPAIR];
        p[(size_t)b * NPAIR] = lo | (hi << 16);
        lo += v & 0xFFFFu;
        hi += v >> 16;
    }
    deg[2 * j]     = (int)lo;
    deg[2 * j + 1] = (int)hi;
}

// single-block exclusive scan of deg -> row_start; row_start[N]=E
__global__ void scan_kernel(const int* __restrict__ deg,
                            int* __restrict__ row_start) {
    __shared__ int part[1024];
    const int tid = threadIdx.x;
    const int chunk = (N_NODES + 1023) / 1024;   // 49
    const int begin = tid * chunk;
    const int end   = min(begin + chunk, N_NODES);
    int s = 0;
    for (int i = begin; i < end; ++i) s += deg[i];
    part[tid] = s;
    __syncthreads();
    for (int d = 1; d < 1024; d <<= 1) {
        int v = (tid >= d) ? part[tid - d] : 0;
        __syncthreads();
        part[tid] += v;
        __syncthreads();
    }
    int run = (tid == 0) ? 0 : part[tid - 1];
    for (int i = begin; i < end; ++i) {
        row_start[i] = run;
        run += deg[i];
    }
    if (tid == 1023) row_start[N_NODES] = part[1023];
}

// pos = row_start[d] + colscan[b][d] + local_rank  -- atomic-free CSR fill.
// 4 sub-blocks per chunk for occupancy (rank is order-independent).
__global__ __launch_bounds__(256) void fill_kernel(const int* __restrict__ src,
                                                   const int* __restrict__ dst,
                                                   const u16* __restrict__ ranks,
                                                   const int* __restrict__ row_start,
                                                   const u32* __restrict__ hist,
                                                   u16* __restrict__ csr) {
    const int b = blockIdx.x >> 2;
    const int q = blockIdx.x & 3;
    const u32* cs = hist + (size_t)b * NPAIR;
    const int base = b * CHUNK + q * (CHUNK / 4);
    for (int i = threadIdx.x; i < CHUNK / 4; i += 256) {
        const int d = dst[base + i];
        const int s = src[base + i];
        const int r = ranks[base + i];
        const int off = (int)((cs[d >> 1] >> ((d & 1) * 16)) & 0xFFFFu);
        csr[row_start[d] + off + r] = (u16)s;
    }
}

// One wave per dst node; lane = bf16x2 channel pair; coalesced 256B row reads.
__global__ __launch_bounds__(256) void gather_kernel(const u32* __restrict__ h2,
                                                     const int* __restrict__ row_start,
                                                     const u16* __restrict__ csr,
                                                     float* __restrict__ z_pad) {
    const int lane = threadIdx.x & 63;
    const int wv   = __builtin_amdgcn_readfirstlane((int)(threadIdx.x >> 6));
    const int gw   = blockIdx.x * 4 + wv;
    const int nw   = gridDim.x * 4;

    float zx = 0.f, zy = 0.f;
    for (int n = gw; n < N_NODES; n += nw) {
        const int rs  = row_start[n];
        const int cnt = row_start[n + 1] - rs;
        const u32 us = h2[n * 64 + lane];          // self loop
        float ax = bflo(us), ay = bfhi(us);
        const u16* lst = csr + rs;
        int i = 0;
        for (; i + 4 <= cnt; i += 4) {
            const int s0 = lst[i], s1 = lst[i + 1], s2 = lst[i + 2], s3 = lst[i + 3];
            const u32 u0 = h2[s0 * 64 + lane];
            const u32 u1 = h2[s1 * 64 + lane];
            const u32 u2 = h2[s2 * 64 + lane];
            const u32 u3 = h2[s3 * 64 + lane];
            ax += bflo(u0) + bflo(u1) + bflo(u2) + bflo(u3);
            ay += bfhi(u0) + bfhi(u1) + bfhi(u2) + bfhi(u3);
        }
        for (; i < cnt; ++i) {
            const u32 u0 = h2[lst[i] * 64 + lane];
            ax += bflo(u0);
            ay += bfhi(u0);
        }
        const float inv = 1.0f / (float)(cnt + 1);
        zx += fmaxf(ax * inv, 0.f);
        zy += fmaxf(ay * inv, 0.f);
    }

    __shared__ float red[4][64][2];
    red[wv][lane][0] = zx;
    red[wv][lane][1] = zy;
    __syncthreads();
    if (threadIdx.x < 64) {
        const float sx = red[0][lane][0] + red[1][lane][0] + red[2][lane][0] + red[3][lane][0];
        const float sy = red[0][lane][1] + red[1][lane][1] + red[2][lane][1] + red[3][lane][1];
        atomicAdd(&z_pad[(2 * lane) * 32], sx);       // 128 slots, 128B apart
        atomicAdd(&z_pad[(2 * lane + 1) * 32], sy);
    }
}

__global__ __launch_bounds__(512) void gru_kernel(const float* __restrict__ z_pad,
                                                  const float* __restrict__ W_ih,
                                                  const float* __restrict__ W_hh,
                                                  const float* __restrict__ b_ih,
                                                  const float* __restrict__ b_hh,
                                                  float* __restrict__ h_state,
                                                  const float* __restrict__ W_cls,
                                                  const float* __restrict__ b_cls,
                                                  float* __restrict__ out,
                                                  int do_cls) {
    __shared__ float zm[128], hs[128], gi[384], gh[384], hn[128];
    const int tid = threadIdx.x;
    if (tid < 128) {
        zm[tid] = z_pad[tid * 32] * (1.0f / (float)N_NODES);
        hs[tid] = h_state[tid];
    }
    __syncthreads();
    if (tid < 384) {
        float a = b_ih[tid], g = b_hh[tid];
        const float* wi = W_ih + tid * 128;
        const float* wh = W_hh + tid * 128;
#pragma unroll 8
        for (int k = 0; k < 128; ++k) {
            a = fmaf(zm[k], wi[k], a);
            g = fmaf(hs[k], wh[k], g);
        }
        gi[tid] = a;
        gh[tid] = g;
    }
    __syncthreads();
    if (tid < 128) {
        const float r  = 1.f / (1.f + expf(-(gi[tid] + gh[tid])));
        const float zg = 1.f / (1.f + expf(-(gi[128 + tid] + gh[128 + tid])));
        const float ng = tanhf(gi[256 + tid] + r * gh[256 + tid]);
        const float hv = (1.f - zg) * ng + zg * hs[tid];
        h_state[tid] = hv;
        hn[tid] = hv;
    }
    __syncthreads();
    if (do_cls && tid < OUT_CH) {
        float a = b_cls[tid];
        const float* wc = W_cls + tid * 128;
#pragma unroll 8
        for (int k = 0; k < 128; ++k) a = fmaf(hn[k], wc[k], a);
        out[tid] = a;
    }
}

extern "C" void kernel_launch(void* const* d_in, const int* in_sizes, int n_in,
                              void* d_out, int out_size, void* d_ws, size_t ws_size,
                              hipStream_t stream) {
    const float* xs    = (const float*)d_in[0];
    const int*   edges = (const int*)d_in[1];
    const float* W_gcn = (const float*)d_in[2];
    const float* b_gcn = (const float*)d_in[3];
    const float* W_ih  = (const float*)d_in[4];
    const float* W_hh  = (const float*)d_in[5];
    const float* b_ih  = (const float*)d_in[6];
    const float* b_hh  = (const float*)d_in[7];
    const float* W_cls = (const float*)d_in[8];
    const float* b_cls = (const float*)d_in[9];
    float* out = (float*)d_out;

    char* ws = (char*)d_ws;
    __hip_bfloat16* h = (__hip_bfloat16*)(ws + OFF_H);
    int*   deg       = (int*)(ws + OFF_DEG);
    float* z_pad     = (float*)(ws + OFF_ZPAD);
    int*   row_start = (int*)(ws + OFF_RS);
    u16*   csr       = (u16*)(ws + OFF_CSR);
    float* h_state   = (float*)(ws + OFF_HST);
    __bf16* wb       = (__bf16*)(ws + OFF_WB);
    u16*   ranks     = (u16*)(ws + OFF_RANKS);
    u32*   hist      = (u32*)(ws + OFF_HIST);

    hipMemsetAsync(h_state, 0, 128 * sizeof(float), stream);
    wbf_kernel<<<64, 256, 0, stream>>>(W_gcn, wb);

    for (int t = 0; t < T_STEPS; ++t) {
        const float* x_t  = xs + (size_t)t * N_NODES * 128;
        const int* src_t  = edges + (size_t)t * 2 * E_EDGES;
        const int* dst_t  = src_t + E_EDGES;

        hipMemsetAsync(z_pad, 0, 16384, stream);

        gemm_mfma_kernel<<<3125, 256, 0, stream>>>(x_t, wb, b_gcn, h);
        hist_rank_kernel<<<NB, 512, 0, stream>>>(dst_t, hist, ranks);
        colscan_kernel<<<(NPAIR + 255) / 256, 256, 0, stream>>>(hist, deg);
        scan_kernel<<<1, 1024, 0, stream>>>(deg, row_start);
        fill_kernel<<<NB * 4, 256, 0, stream>>>(src_t, dst_t, ranks, row_start, hist, csr);
        gather_kernel<<<2048, 256, 0, stream>>>((const u32*)h, row_start, csr, z_pad);
        gru_kernel<<<1, 512, 0, stream>>>(z_pad, W_ih, W_hh, b_ih, b_hh, h_state,
                                          W_cls, b_cls, out, (t == T_STEPS - 1) ? 1 : 0);
    }
}

// Round 6
// 1014.887 us; speedup vs baseline: 2.2428x; 1.2407x over previous
//
#include <hip/hip_runtime.h>
#include <hip/hip_bf16.h>

typedef unsigned int u32;
typedef unsigned short u16;
typedef __attribute__((ext_vector_type(8))) __bf16 bfrag;   // 8 bf16 = 4 VGPRs (MFMA A/B operand)
typedef __attribute__((ext_vector_type(4))) float f32x4;    // MFMA C/D

#define T_STEPS 4
#define N_NODES 50000
#define E_EDGES 1600000
#define HID 128
#define OUT_CH 16

#define NB 128                   // hist blocks; chunk = E/NB
#define CHUNK (E_EDGES / NB)     // 12500
#define NPAIR (N_NODES / 2)      // 25000 packed u16-pair histogram entries
#define SCAN4 13                 // int4s per thread in scan (1024*13=13312 >= 12500)

// ---- workspace layout (bytes) ----
#define OFF_H     0u            // h bf16 [N*128]             = 12,800,000
#define OFF_DEG   12800000u     // deg [13312 int4 padded]    = 212,992
#define OFF_RS    13012992u     // row_start [13312 int4]     = 212,992
#define OFF_ZPAD  13225984u     // z_sum padded [128*32] f32  = 16,384
#define OFF_CSR   13242368u     // csr src [E] u16            = 3,200,000
#define OFF_HST   16442368u     // h_state [128] f32          = 512
#define OFF_WB    16442880u     // W_gcn bf16 [128*128]       = 32,768
#define OFF_RANKS 16475648u     // ranks [E] u16              = 3,200,000
#define OFF_HIST  19675648u     // hist [NB][NPAIR] u32       = 12,800,000 (end ~32.5 MB)

__device__ __forceinline__ float bflo(u32 u) { return __uint_as_float(u << 16); }
__device__ __forceinline__ float bfhi(u32 u) { return __uint_as_float(u & 0xFFFF0000u); }

// one-shot: W fp32 -> bf16 (32 KB, L1-resident for the GEMM)
__global__ void wbf_kernel(const float* __restrict__ W, __bf16* __restrict__ wb) {
    const int i = blockIdx.x * 256 + threadIdx.x;   // 16384
    wb[i] = (__bf16)W[i];
}

// h = bf16(x @ W^T + b) via MFMA 16x16x32 bf16.
// Block = 16-row m-tile (3125 blocks), 4 waves; wave wv covers output cols [32wv,32wv+32).
// Frag layouts (m89/m120-verified): A[m=lane&15][k=(lane>>4)*8+j],
// B[n=lane&15][k=(lane>>4)*8+j], C/D row=(lane>>4)*4+reg, col=lane&15.
__global__ __launch_bounds__(256) void gemm_mfma_kernel(const float* __restrict__ x,
                                                        const __bf16* __restrict__ wb,
                                                        const float* __restrict__ b,
                                                        __hip_bfloat16* __restrict__ h) {
    const int lane = threadIdx.x & 63;
    const int wv   = threadIdx.x >> 6;      // 0..3 -> n-slice
    const int r16  = lane & 15;
    const int quad = lane >> 4;
    const int mb   = blockIdx.x;            // rows [16mb, 16mb+16)

    bfrag Bf[2][4];
#pragma unroll
    for (int nt = 0; nt < 2; ++nt) {
        const int c = wv * 32 + nt * 16 + r16;
#pragma unroll
        for (int ks = 0; ks < 4; ++ks)
            Bf[nt][ks] = *(const bfrag*)(wb + c * 128 + ks * 32 + quad * 8);
    }

    const float* xp = x + (size_t)(mb * 16 + r16) * 128 + quad * 8;
    bfrag Af[4];
#pragma unroll
    for (int ks = 0; ks < 4; ++ks) {
        const float* ap = xp + ks * 32;
#pragma unroll
        for (int j = 0; j < 8; ++j) Af[ks][j] = (__bf16)ap[j];
    }

    f32x4 acc0 = {0.f, 0.f, 0.f, 0.f};
    f32x4 acc1 = {0.f, 0.f, 0.f, 0.f};
#pragma unroll
    for (int ks = 0; ks < 4; ++ks) {
        acc0 = __builtin_amdgcn_mfma_f32_16x16x32_bf16(Af[ks], Bf[0][ks], acc0, 0, 0, 0);
        acc1 = __builtin_amdgcn_mfma_f32_16x16x32_bf16(Af[ks], Bf[1][ks], acc1, 0, 0, 0);
    }

    const int c0 = wv * 32 + r16;
    const float b0 = b[c0], b1 = b[c0 + 16];
#pragma unroll
    for (int r = 0; r < 4; ++r) {
        const int row = mb * 16 + quad * 4 + r;
        h[(size_t)row * 128 + c0]      = __float2bfloat16(acc0[r] + b0);
        h[(size_t)row * 128 + c0 + 16] = __float2bfloat16(acc1[r] + b1);
    }
}

// Block b: LDS histogram of its 12500-edge chunk (u16 counts packed 2/u32),
// LDS-atomic return = local rank. No global atomics (R3 lesson: 1.6M
// device-scope atomics = 103 MB EA round-trips).
__global__ __launch_bounds__(512) void hist_rank_kernel(const int* __restrict__ dst,
                                                        u32* __restrict__ hist,
                                                        u16* __restrict__ ranks) {
    __shared__ u32 hloc[NPAIR / 2];          // 12500 u32 = 50 KB
    const int b = blockIdx.x;
    const int base = b * CHUNK;
    u32* row = hist + (size_t)b * NPAIR;

#pragma unroll
    for (int half = 0; half < 2; ++half) {
        for (int j = threadIdx.x; j < NPAIR / 2; j += 512) hloc[j] = 0;
        __syncthreads();
        const int jlo = half * (NPAIR / 2);
        for (int i = threadIdx.x; i < CHUNK; i += 512) {
            const int d = dst[base + i];
            const int j = d >> 1;
            if ((j >= jlo) && (j < jlo + NPAIR / 2)) {
                const u32 inc = (d & 1) ? 0x10000u : 1u;
                const u32 old = atomicAdd(&hloc[j - jlo], inc);
                ranks[base + i] = (u16)((old >> ((d & 1) * 16)) & 0xFFFFu);
            }
        }
        __syncthreads();
        for (int j = threadIdx.x; j < NPAIR / 2; j += 512) row[jlo + j] = hloc[j];
        __syncthreads();
    }
}

// In-place exclusive scan over the NB block-rows for each node pair; emits deg.
__global__ void colscan_kernel(u32* __restrict__ hist, int* __restrict__ deg) {
    const int j = blockIdx.x * blockDim.x + threadIdx.x;
    if (j >= NPAIR) return;
    u32 lo = 0, hi = 0;
    u32* p = hist + j;
#pragma unroll 8
    for (int b = 0; b < NB; ++b) {
        const u32 v = p[(size_t)b * NPAIR];
        p[(size_t)b * NPAIR] = lo | (hi << 16);
        lo += v & 0xFFFFu;
        hi += v >> 16;
    }
    deg[2 * j]     = (int)lo;
    deg[2 * j + 1] = (int)hi;
}

// Single-block scan, fully unrolled + vectorized (R5 lesson: dynamic-trip
// scalar loops serialize ~100 L2/HBM round-trips -> 79 us). 13 int4/thread,
// all loads in flight before one waitcnt; deg tail [50000,53248) pre-zeroed.
// row_start[50000]=E falls out of the zero tail.
__global__ __launch_bounds__(1024) void scan_kernel(const int4* __restrict__ deg4,
                                                    int4* __restrict__ rs4) {
    __shared__ int part[1024];
    const int tid = threadIdx.x;
    int4 v[SCAN4];
#pragma unroll
    for (int j = 0; j < SCAN4; ++j) v[j] = deg4[tid * SCAN4 + j];
    int s = 0;
#pragma unroll
    for (int j = 0; j < SCAN4; ++j) s += v[j].x + v[j].y + v[j].z + v[j].w;
    part[tid] = s;
    __syncthreads();
    for (int d = 1; d < 1024; d <<= 1) {
        const int t = (tid >= d) ? part[tid - d] : 0;
        __syncthreads();
        part[tid] += t;
        __syncthreads();
    }
    int run = (tid == 0) ? 0 : part[tid - 1];
#pragma unroll
    for (int j = 0; j < SCAN4; ++j) {
        int4 o;
        o.x = run; run += v[j].x;
        o.y = run; run += v[j].y;
        o.z = run; run += v[j].z;
        o.w = run; run += v[j].w;
        rs4[tid * SCAN4 + j] = o;
    }
}

// pos = row_start[d] + colscan[b][d] + local_rank  -- atomic-free CSR fill.
__global__ __launch_bounds__(256) void fill_kernel(const int* __restrict__ src,
                                                   const int* __restrict__ dst,
                                                   const u16* __restrict__ ranks,
                                                   const int* __restrict__ row_start,
                                                   const u32* __restrict__ hist,
                                                   u16* __restrict__ csr) {
    const int b = blockIdx.x >> 2;
    const int q = blockIdx.x & 3;
    const u32* cs = hist + (size_t)b * NPAIR;
    const int base = b * CHUNK + q * (CHUNK / 4);
    for (int i = threadIdx.x; i < CHUNK / 4; i += 256) {
        const int d = dst[base + i];
        const int s = src[base + i];
        const int r = ranks[base + i];
        const int off = (int)((cs[d >> 1] >> ((d & 1) * 16)) & 0xFFFFu);
        csr[row_start[d] + off + r] = (u16)s;
    }
}

// One wave per dst node; lane = bf16x2 channel pair; coalesced 256B row reads.
__global__ __launch_bounds__(256) void gather_kernel(const u32* __restrict__ h2,
                                                     const int* __restrict__ row_start,
                                                     const u16* __restrict__ csr,
                                                     float* __restrict__ z_pad) {
    const int lane = threadIdx.x & 63;
    const int wv   = __builtin_amdgcn_readfirstlane((int)(threadIdx.x >> 6));
    const int gw   = blockIdx.x * 4 + wv;
    const int nw   = gridDim.x * 4;

    float zx = 0.f, zy = 0.f;
    for (int n = gw; n < N_NODES; n += nw) {
        const int rs  = row_start[n];
        const int cnt = row_start[n + 1] - rs;
        const u32 us = h2[n * 64 + lane];          // self loop
        float ax = bflo(us), ay = bfhi(us);
        const u16* lst = csr + rs;
        int i = 0;
        for (; i + 4 <= cnt; i += 4) {
            const int s0 = lst[i], s1 = lst[i + 1], s2 = lst[i + 2], s3 = lst[i + 3];
            const u32 u0 = h2[s0 * 64 + lane];
            const u32 u1 = h2[s1 * 64 + lane];
            const u32 u2 = h2[s2 * 64 + lane];
            const u32 u3 = h2[s3 * 64 + lane];
            ax += bflo(u0) + bflo(u1) + bflo(u2) + bflo(u3);
            ay += bfhi(u0) + bfhi(u1) + bfhi(u2) + bfhi(u3);
        }
        for (; i < cnt; ++i) {
            const u32 u0 = h2[lst[i] * 64 + lane];
            ax += bflo(u0);
            ay += bfhi(u0);
        }
        const float inv = 1.0f / (float)(cnt + 1);
        zx += fmaxf(ax * inv, 0.f);
        zy += fmaxf(ay * inv, 0.f);
    }

    __shared__ float red[4][64][2];
    red[wv][lane][0] = zx;
    red[wv][lane][1] = zy;
    __syncthreads();
    if (threadIdx.x < 64) {
        const float sx = red[0][lane][0] + red[1][lane][0] + red[2][lane][0] + red[3][lane][0];
        const float sy = red[0][lane][1] + red[1][lane][1] + red[2][lane][1] + red[3][lane][1];
        atomicAdd(&z_pad[(2 * lane) * 32], sx);       // 128 slots, 128B apart
        atomicAdd(&z_pad[(2 * lane + 1) * 32], sy);
    }
}

__global__ __launch_bounds__(512) void gru_kernel(const float* __restrict__ z_pad,
                                                  const float* __restrict__ W_ih,
                                                  const float* __restrict__ W_hh,
                                                  const float* __restrict__ b_ih,
                                                  const float* __restrict__ b_hh,
                                                  float* __restrict__ h_state,
                                                  const float* __restrict__ W_cls,
                                                  const float* __restrict__ b_cls,
                                                  float* __restrict__ out,
                                                  int do_cls) {
    __shared__ float zm[128], hs[128], gi[384], gh[384], hn[128];
    const int tid = threadIdx.x;
    if (tid < 128) {
        zm[tid] = z_pad[tid * 32] * (1.0f / (float)N_NODES);
        hs[tid] = h_state[tid];
    }
    __syncthreads();
    if (tid < 384) {
        float a = b_ih[tid], g = b_hh[tid];
        const float* wi = W_ih + tid * 128;
        const float* wh = W_hh + tid * 128;
#pragma unroll 8
        for (int k = 0; k < 128; ++k) {
            a = fmaf(zm[k], wi[k], a);
            g = fmaf(hs[k], wh[k], g);
        }
        gi[tid] = a;
        gh[tid] = g;
    }
    __syncthreads();
    if (tid < 128) {
        const float r  = 1.f / (1.f + expf(-(gi[tid] + gh[tid])));
        const float zg = 1.f / (1.f + expf(-(gi[128 + tid] + gh[128 + tid])));
        const float ng = tanhf(gi[256 + tid] + r * gh[256 + tid]);
        const float hv = (1.f - zg) * ng + zg * hs[tid];
        h_state[tid] = hv;
        hn[tid] = hv;
    }
    __syncthreads();
    if (do_cls && tid < OUT_CH) {
        float a = b_cls[tid];
        const float* wc = W_cls + tid * 128;
#pragma unroll 8
        for (int k = 0; k < 128; ++k) a = fmaf(hn[k], wc[k], a);
        out[tid] = a;
    }
}

extern "C" void kernel_launch(void* const* d_in, const int* in_sizes, int n_in,
                              void* d_out, int out_size, void* d_ws, size_t ws_size,
                              hipStream_t stream) {
    const float* xs    = (const float*)d_in[0];
    const int*   edges = (const int*)d_in[1];
    const float* W_gcn = (const float*)d_in[2];
    const float* b_gcn = (const float*)d_in[3];
    const float* W_ih  = (const float*)d_in[4];
    const float* W_hh  = (const float*)d_in[5];
    const float* b_ih  = (const float*)d_in[6];
    const float* b_hh  = (const float*)d_in[7];
    const float* W_cls = (const float*)d_in[8];
    const float* b_cls = (const float*)d_in[9];
    float* out = (float*)d_out;

    char* ws = (char*)d_ws;
    __hip_bfloat16* h = (__hip_bfloat16*)(ws + OFF_H);
    int*   deg       = (int*)(ws + OFF_DEG);
    int*   row_start = (int*)(ws + OFF_RS);
    float* z_pad     = (float*)(ws + OFF_ZPAD);
    u16*   csr       = (u16*)(ws + OFF_CSR);
    float* h_state   = (float*)(ws + OFF_HST);
    __bf16* wb       = (__bf16*)(ws + OFF_WB);
    u16*   ranks     = (u16*)(ws + OFF_RANKS);
    u32*   hist      = (u32*)(ws + OFF_HIST);

    hipMemsetAsync(h_state, 0, 128 * sizeof(float), stream);
    // zero deg tail [50000, 13312*4): ws re-poisoned 0xAA before every launch
    hipMemsetAsync((char*)deg + 200000, 0, 13312 * 16 - 200000, stream);
    wbf_kernel<<<64, 256, 0, stream>>>(W_gcn, wb);

    for (int t = 0; t < T_STEPS; ++t) {
        const float* x_t  = xs + (size_t)t * N_NODES * 128;
        const int* src_t  = edges + (size_t)t * 2 * E_EDGES;
        const int* dst_t  = src_t + E_EDGES;

        hipMemsetAsync(z_pad, 0, 16384, stream);

        gemm_mfma_kernel<<<3125, 256, 0, stream>>>(x_t, wb, b_gcn, h);
        hist_rank_kernel<<<NB, 512, 0, stream>>>(dst_t, hist, ranks);
        colscan_kernel<<<(NPAIR + 255) / 256, 256, 0, stream>>>(hist, deg);
        scan_kernel<<<1, 1024, 0, stream>>>((const int4*)deg, (int4*)row_start);
        fill_kernel<<<NB * 4, 256, 0, stream>>>(src_t, dst_t, ranks, row_start, hist, csr);
        gather_kernel<<<2048, 256, 0, stream>>>((const u32*)h, row_start, csr, z_pad);
        gru_kernel<<<1, 512, 0, stream>>>(z_pad, W_ih, W_hh, b_ih, b_hh, h_state,
                                          W_cls, b_cls, out, (t == T_STEPS - 1) ? 1 : 0);
    }
}